// Round 11
// baseline (254.960 us; speedup 1.0000x reference)
//
#include <hip/hip_runtime.h>
#include <hip/hip_bf16.h>
#include <stdint.h>

// ---------------------------------------------------------------------------
// SpecWaveTransformer on MI355X.
// B=2 C=8 MAPS=4 HEADS=8 F=256 W=1024 HD=32.  Outputs: out[2,8,256,1024] f32,
// qk[2,4,8,1024,1024] f32 (concatenated in d_out).
// ---------------------------------------------------------------------------

typedef __attribute__((ext_vector_type(8))) short s16x8;
typedef __attribute__((ext_vector_type(4))) float f32x4;

#define MFMA16(a, b, c) __builtin_amdgcn_mfma_f32_16x16x32_bf16((a), (b), (c), 0, 0, 0)

__device__ __forceinline__ short f2bf(float f) {
  unsigned u = __builtin_bit_cast(unsigned, f);
  u = (u + 0x7FFFu + ((u >> 16) & 1u)) >> 16;
  return (short)u;
}
__device__ __forceinline__ unsigned pack2(float a, float b) {
  return (unsigned)(unsigned short)f2bf(a) | ((unsigned)(unsigned short)f2bf(b) << 16);
}
__device__ __forceinline__ float bf2f(unsigned u) {
  return __builtin_bit_cast(float, u << 16);
}

// ---------------------------------------------------------------------------
// helper: conv row loader
// ---------------------------------------------------------------------------
__device__ __forceinline__ void loadrow(float* r, const float* xc, int f, int w0) {
  if (f < 0 || f > 255) {
#pragma unroll
    for (int jj = 0; jj < 6; ++jj) r[jj] = 0.f;
    return;
  }
  const float* row = xc + f * 1024;
#pragma unroll
  for (int jj = 0; jj < 6; ++jj) {
    int wc = w0 - 1 + jj;
    r[jj] = (wc >= 0 && wc < 1024) ? row[wc] : 0.f;
  }
}

// ---------------------------------------------------------------------------
// K_pre: FUSED prep (bf16 weight casts + RoPE table) | conv3x3 (all 3 p per
// block) | x-transpose.  All three are mutually independent -> one dispatch.
// blocks: [0,3072) prep, [3072,3584) conv, [3584,4608) tx.
// ---------------------------------------------------------------------------
__global__ __launch_bounds__(256) void k_pre(const float* x,
                                             const float* wq, const float* wk,
                                             const float* wv, const float* wo,
                                             const float* wqc, const float* bq,
                                             const float* wkc, const float* bk,
                                             const float* wvc, const float* bv,
                                             short* wlin, short* wob, float* ct, float* st,
                                             short* y, short* xT) {
  __shared__ short tile[64][66];
  int B = blockIdx.x;
  int tid = threadIdx.x;

  if (B < 3072) {  // ---- prep ----
    int i = B * 256 + tid;
    if (i < 262144) wlin[i] = f2bf(wq[i]);
    else if (i < 524288) wlin[i] = f2bf(wk[i - 262144]);
    else if (i < 786432) wlin[i] = f2bf(wv[i - 524288]);
    if (i < 786432) wob[i] = f2bf(wo[i]);
    if (i < 16384) {
      int w = i >> 4, j = i & 15;
      float inv = exp2f(-(float)j * (13.287712379549449f / 16.0f));
      float ang = (float)w * inv;
      ct[i] = cosf(ang);
      st[i] = sinf(ang);
    }
    return;
  }

  if (B < 3584) {  // ---- conv ----
    int blk = B - 3072;  // 512 = 4 m * 2 b * 64 fstrips
    int m_ = blk >> 7;
    int b_ = (blk >> 6) & 1;
    int fs = blk & 63;
    int f0 = fs * 4;
    int w0 = tid * 4;
    const float* xb = x + (size_t)b_ * 2097152;
    const float* wp_[3] = {wqc + m_ * 72, wkc + m_ * 72, wvc + m_ * 72};
    float bias_[3] = {bq[m_], bk[m_], bv[m_]};

    float acc[3][4][4];
#pragma unroll
    for (int p = 0; p < 3; ++p)
#pragma unroll
      for (int fi = 0; fi < 4; ++fi)
#pragma unroll
        for (int j = 0; j < 4; ++j) acc[p][fi][j] = bias_[p];

    for (int c = 0; c < 8; ++c) {
      const float* xc = xb + c * 262144;
      float w9[3][9];
#pragma unroll
      for (int p = 0; p < 3; ++p)
#pragma unroll
        for (int t = 0; t < 9; ++t) w9[p][t] = wp_[p][c * 9 + t];
      float rows[6][6];
#pragma unroll
      for (int ri = 0; ri < 6; ++ri) loadrow(rows[ri], xc, f0 - 1 + ri, w0);
#pragma unroll
      for (int fi = 0; fi < 4; ++fi) {
#pragma unroll
        for (int p = 0; p < 3; ++p) {
#pragma unroll
          for (int j = 0; j < 4; ++j) {
            float s = acc[p][fi][j];
            s += rows[fi][j] * w9[p][0] + rows[fi][j + 1] * w9[p][1] + rows[fi][j + 2] * w9[p][2];
            s += rows[fi + 1][j] * w9[p][3] + rows[fi + 1][j + 1] * w9[p][4] + rows[fi + 1][j + 2] * w9[p][5];
            s += rows[fi + 2][j] * w9[p][6] + rows[fi + 2][j + 1] * w9[p][7] + rows[fi + 2][j + 2] * w9[p][8];
            acc[p][fi][j] = s;
          }
        }
      }
    }
#pragma unroll
    for (int p = 0; p < 3; ++p) {
      int mat = p * 8 + b_ * 4 + m_;
      short* yp = y + (size_t)mat * 262144;
#pragma unroll
      for (int fi = 0; fi < 4; ++fi) {
        uint2 pk;
        pk.x = pack2(acc[p][fi][0], acc[p][fi][1]);
        pk.y = pack2(acc[p][fi][2], acc[p][fi][3]);
        *(uint2*)(yp + (f0 + fi) * 1024 + w0) = pk;
      }
    }
    return;
  }

  {  // ---- tx: x f32 [f][w] -> xT bf16 [w][f] ----
    int blk = B - 3584;  // 16 * 64
    int mat = blk >> 6;
    int t = blk & 63;
    int f0 = (t >> 4) * 64, w0 = (t & 15) * 64;
    int j = tid & 63, i0 = tid >> 6;
    const float* sp = x + (size_t)mat * 262144 + f0 * 1024 + w0;
#pragma unroll
    for (int k = 0; k < 16; ++k) {
      int i = i0 + k * 4;
      tile[j][i] = f2bf(sp[i * 1024 + j]);
    }
    __syncthreads();
    short* dp = xT + (size_t)mat * 262144 + w0 * 256 + f0;
#pragma unroll
    for (int k = 0; k < 16; ++k) {
      int i = i0 + k * 4;
      dp[i * 256 + j] = tile[i][j];
    }
  }
}

// ---------------------------------------------------------------------------
// K2: y[f][w] -> yT[w][f] (bf16)
// ---------------------------------------------------------------------------
__global__ __launch_bounds__(256) void k_ty(const short* y, short* yT) {
  __shared__ short tile[64][66];
  int blk = blockIdx.x;  // 24 * 64
  int mat = blk >> 6;
  int t = blk & 63;
  int f0 = (t >> 4) * 64, w0 = (t & 15) * 64;
  int j = threadIdx.x & 63, i0 = threadIdx.x >> 6;
  const short* sp = y + (size_t)mat * 262144 + f0 * 1024 + w0;
#pragma unroll
  for (int k = 0; k < 16; ++k) {
    int i = i0 + k * 4;
    tile[j][i] = sp[i * 1024 + j];
  }
  __syncthreads();
  short* dp = yT + (size_t)mat * 262144 + w0 * 256 + f0;
#pragma unroll
  for (int k = 0; k < 16; ++k) {
    int i = i0 + k * 4;
    dp[i * 256 + j] = tile[i][j];
  }
}

// ---------------------------------------------------------------------------
// K3: per-map linear (MFMA GEMM) + RoPE (+1/16 scale on Q).
// ---------------------------------------------------------------------------
__global__ __launch_bounds__(256) void k_qkv(const short* wlin, const short* yT,
                                             const float* ct, const float* st,
                                             short* qws, short* kws, short* vws) {
  int blk = blockIdx.x;  // 24 pbm * 16 wtiles
  int pbm = blk >> 4, wt = blk & 15;
  int p = pbm >> 3, bm = pbm & 7;
  int m_ = bm & 3;
  int tid = threadIdx.x, wv = tid >> 6, l = tid & 63, lr = l & 15, lg = l >> 4;
  const short* wl = wlin + (p * 4 + m_) * 65536;
  const short* yp = yT + (size_t)pbm * 262144;
  int w0 = wt * 64;
  int G0 = wv * 64;
  f32x4 acc[4][4];
#pragma unroll
  for (int i = 0; i < 4; ++i)
#pragma unroll
    for (int j = 0; j < 4; ++j) acc[i][j] = (f32x4){0.f, 0.f, 0.f, 0.f};

  if (p < 2) {
    for (int kc = 0; kc < 256; kc += 32) {
      s16x8 A[4], Bf[4];
#pragma unroll
      for (int gs = 0; gs < 4; ++gs)
        A[gs] = *(const s16x8*)(wl + (G0 + gs * 16 + lr) * 256 + kc + lg * 8);
#pragma unroll
      for (int s = 0; s < 4; ++s)
        Bf[s] = *(const s16x8*)(yp + (w0 + s * 16 + lr) * 256 + kc + lg * 8);
#pragma unroll
      for (int gs = 0; gs < 4; ++gs)
#pragma unroll
        for (int s = 0; s < 4; ++s) acc[gs][s] = MFMA16(A[gs], Bf[s], acc[gs][s]);
    }
    short* dst = (p == 0) ? qws : kws;
    float scale = (p == 0) ? 0.0625f : 1.0f;  // fold 1/sqrt(256) into Q
#pragma unroll
    for (int gs = 0; gs < 4; ++gs) {
      int g0v = G0 + gs * 16 + lg * 4;
      int h = g0v >> 5, d0 = g0v & 31;
      int i0 = d0 >> 1;
#pragma unroll
      for (int s = 0; s < 4; ++s) {
        int w = w0 + s * 16 + lr;
        float c0 = ct[w * 16 + i0], sn0 = st[w * 16 + i0];
        float c1 = ct[w * 16 + i0 + 1], sn1 = st[w * 16 + i0 + 1];
        f32x4 v = acc[gs][s];
        float e0 = (v[0] * c0 - v[1] * sn0) * scale;
        float e1 = (v[1] * c0 + v[0] * sn0) * scale;
        float e2 = (v[2] * c1 - v[3] * sn1) * scale;
        float e3 = (v[3] * c1 + v[2] * sn1) * scale;
        uint2 pk;
        pk.x = pack2(e0, e1);
        pk.y = pack2(e2, e3);
        *(uint2*)(dst + (((size_t)bm * 8 + h) * 1024 + w) * 32 + d0) = pk;
      }
    }
  } else {
    for (int kc = 0; kc < 256; kc += 32) {
      s16x8 A[4], Bf[4];
#pragma unroll
      for (int s = 0; s < 4; ++s)
        A[s] = *(const s16x8*)(yp + (w0 + s * 16 + lr) * 256 + kc + lg * 8);
#pragma unroll
      for (int gs = 0; gs < 4; ++gs)
        Bf[gs] = *(const s16x8*)(wl + (G0 + gs * 16 + lr) * 256 + kc + lg * 8);
#pragma unroll
      for (int s = 0; s < 4; ++s)
#pragma unroll
        for (int gs = 0; gs < 4; ++gs) acc[s][gs] = MFMA16(A[s], Bf[gs], acc[s][gs]);
    }
#pragma unroll
    for (int s = 0; s < 4; ++s) {
      int wb = w0 + s * 16 + lg * 4;
#pragma unroll
      for (int gs = 0; gs < 4; ++gs) {
        int g = G0 + gs * 16 + lr;
        f32x4 v = acc[s][gs];
        uint2 pk;
        pk.x = pack2(v[0], v[1]);
        pk.y = pack2(v[2], v[3]);
        *(uint2*)(vws + ((size_t)bm * 256 + g) * 1024 + wb) = pk;
      }
    }
  }
}

// ---------------------------------------------------------------------------
// K4: fused attention — burst-batched r/w (last untested axis: R2..R10 all
// interleaved ~4KB read/write at constant offset -> HBM bus-turnaround /
// channel ping-pong suspected; all variants pinned at 2.6 TB/s).
// Phase 1: QK^T -> S strip bf16 [16 q][2048B] LDS (XOR swz), per wave.
// Phase 2: rows in 4-row groups, double-buffered: [16 LDS reads + adds] ->
//          [16-store 16KB WRITE BURST] -> [16-load 16KB READ BURST (g+2)] ->
//          [exp/pack/rowsum, no vmem].
// Phase 3: PV from P strip + V (L2), normalize, write aT.
// Zero barriers; wave-private LDS strips; all reg arrays statically indexed.
// ---------------------------------------------------------------------------
__global__ __launch_bounds__(256, 1) void k_attn(const short* qws, const short* kws,
                                                 const short* vws, const float* prev,
                                                 float* qko, short* aT) {
  __shared__ char smem[131072];  // 4 waves x 32KB S/P strip
  int blk = blockIdx.x;  // 1024 = 64 bmh * 16 qg
  int bmh = blk >> 4;
  int qg = blk & 15;
  int h = bmh & 7, bm = bmh >> 3;
  int tid = threadIdx.x;
  int wv = tid >> 6, l = tid & 63, lr = l & 15, lg = l >> 4;
  int q0 = qg * 64 + wv * 16;
  const short* qp = qws + (size_t)bmh * 32768;
  const short* kp = kws + (size_t)bmh * 32768;
  const short* vp = vws + ((size_t)bm * 256 + h * 32) * 1024;
  const float* pvb = prev + (size_t)bmh * 1048576 + (size_t)q0 * 1024;
  float* qob = qko + (size_t)bmh * 1048576 + (size_t)q0 * 1024;
  char* Sb = smem + wv * 32768;  // byte(q,kb) = q*2048 + (kb ^ ((q&7)<<4))

  s16x8 qf = *(const s16x8*)(qp + (q0 + lr) * 32 + lg * 8);
  const f32x4 z4 = {0.f, 0.f, 0.f, 0.f};

  // ---- Phase 1: QK^T -> S strip (bf16) ----
#pragma unroll
  for (int w = 0; w < 16; ++w) {
    int k0 = w * 64;
    s16x8 kf[4];
#pragma unroll
    for (int s = 0; s < 4; ++s)
      kf[s] = *(const s16x8*)(kp + (k0 + s * 16 + lr) * 32 + lg * 8);
#pragma unroll
    for (int s = 0; s < 4; ++s) {
      f32x4 sx = MFMA16(kf[s], qf, z4);  // lane: q=lr, k=k0+s*16+lg*4+reg
      uint2 pk;
      pk.x = pack2(sx[0], sx[1]);
      pk.y = pack2(sx[2], sx[3]);
      int kb = (k0 + s * 16 + lg * 4) * 2;
      *(uint2*)(Sb + lr * 2048 + (kb ^ ((lr & 7) << 4))) = pk;
    }
  }

  // ---- Phase 2: burst-batched row-IO (4-row groups, double-buffered) ----
  float rs[16];
  f32x4 pA[4][4], pB[4][4];
#pragma unroll
  for (int r4 = 0; r4 < 4; ++r4)
#pragma unroll
    for (int qt = 0; qt < 4; ++qt)
      pA[r4][qt] = *(const f32x4*)(pvb + (size_t)r4 * 1024 + qt * 256 + l * 4);
#pragma unroll
  for (int r4 = 0; r4 < 4; ++r4)
#pragma unroll
    for (int qt = 0; qt < 4; ++qt)
      pB[r4][qt] = *(const f32x4*)(pvb + (size_t)(4 + r4) * 1024 + qt * 256 + l * 4);

#pragma unroll
  for (int g = 0; g < 4; ++g) {
    f32x4(&cur)[4][4] = (g & 1) ? pB : pA;
    // (1) LDS reads + add
    f32x4 v[4][4];
#pragma unroll
    for (int r4 = 0; r4 < 4; ++r4) {
      int r = g * 4 + r4;
#pragma unroll
      for (int qt = 0; qt < 4; ++qt) {
        int sb = (qt * 512 + l * 8) ^ ((r & 7) << 4);
        uint2 su = *(const uint2*)(Sb + r * 2048 + sb);
        f32x4 sv = {bf2f(su.x & 0xffffu), bf2f(su.x >> 16),
                    bf2f(su.y & 0xffffu), bf2f(su.y >> 16)};
        v[r4][qt] = sv + cur[r4][qt];
      }
    }
    // (2) 16-store write burst (16KB contiguous region)
#pragma unroll
    for (int r4 = 0; r4 < 4; ++r4)
#pragma unroll
      for (int qt = 0; qt < 4; ++qt)
        __builtin_nontemporal_store(v[r4][qt],
            (f32x4*)(qob + (size_t)(g * 4 + r4) * 1024 + qt * 256 + l * 4));
    // (3) 16-load read burst for group g+2
    if (g < 2) {
#pragma unroll
      for (int r4 = 0; r4 < 4; ++r4)
#pragma unroll
        for (int qt = 0; qt < 4; ++qt)
          cur[r4][qt] = *(const f32x4*)(pvb + (size_t)((g + 2) * 4 + r4) * 1024 + qt * 256 + l * 4);
    }
    // (4) exp + pack + P write + rowsum (pure VALU/LDS)
#pragma unroll
    for (int r4 = 0; r4 < 4; ++r4) {
      int r = g * 4 + r4;
      float sum = 0.f;
#pragma unroll
      for (int qt = 0; qt < 4; ++qt) {
        f32x4 w_ = v[r4][qt];
        float e0 = __expf(w_[0]), e1 = __expf(w_[1]);
        float e2 = __expf(w_[2]), e3 = __expf(w_[3]);
        sum += (e0 + e1) + (e2 + e3);
        uint2 pk;
        pk.x = pack2(e0, e1);
        pk.y = pack2(e2, e3);
        int sb = (qt * 512 + l * 8) ^ ((r & 7) << 4);
        *(uint2*)(Sb + r * 2048 + sb) = pk;  // P in-place over S
      }
      rs[r] = sum;
    }
  }
  // reduce rowsums across all 64 lanes
#pragma unroll
  for (int r = 0; r < 16; ++r) {
    float s = rs[r];
    s += __shfl_xor(s, 1);
    s += __shfl_xor(s, 2);
    s += __shfl_xor(s, 4);
    s += __shfl_xor(s, 8);
    s += __shfl_xor(s, 16);
    s += __shfl_xor(s, 32);
    rs[r] = s;
  }

  // ---- Phase 3: PV from P strip (LDS) + V (L2) ----
  f32x4 o0 = {0.f, 0.f, 0.f, 0.f}, o1 = {0.f, 0.f, 0.f, 0.f};
#pragma unroll
  for (int w = 0; w < 16; ++w) {
    int k0 = w * 64;
#pragma unroll
    for (int kc = 0; kc < 2; ++kc) {
      int kb = (k0 + kc * 32 + lg * 8) * 2;
      s16x8 pa = *(const s16x8*)(Sb + lr * 2048 + (kb ^ ((lr & 7) << 4)));
      s16x8 vf0 = *(const s16x8*)(vp + lr * 1024 + k0 + kc * 32 + lg * 8);
      o0 = MFMA16(pa, vf0, o0);
      s16x8 vf1 = *(const s16x8*)(vp + (16 + lr) * 1024 + k0 + kc * 32 + lg * 8);
      o1 = MFMA16(pa, vf1, o1);
    }
  }
  // normalize: output q-row = lg*4+j (static select)
#pragma unroll
  for (int j = 0; j < 4; ++j) {
    float s = (lg == 0) ? rs[j] : (lg == 1) ? rs[4 + j] : (lg == 2) ? rs[8 + j] : rs[12 + j];
    float inv = 1.0f / s;
    o0[j] *= inv;
    o1[j] *= inv;
  }
  short* ap = aT + (size_t)bm * 262144;
#pragma unroll
  for (int r = 0; r < 4; ++r) {
    int row = q0 + lg * 4 + r;
    ap[row * 256 + h * 32 + lr] = f2bf(o0[r]);
    ap[row * 256 + h * 32 + 16 + lr] = f2bf(o1[r]);
  }
}

// ---------------------------------------------------------------------------
// K5: z[b][c][g][w] = sum_f wo_pw[c][g][f] * cat[b][c][f][w]  (bf16 z output)
// ---------------------------------------------------------------------------
__global__ __launch_bounds__(256) void k_zproj(const short* wopw, const short* xT,
                                               const short* aT, short* z) {
  int blk = blockIdx.x;  // 24 bc * 16 wtiles
  int bc = blk >> 4, wt = blk & 15;
  int b_ = bc / 12, c_ = bc % 12;
  const short* src = (c_ < 8) ? (xT + ((size_t)b_ * 8 + c_) * 262144)
                              : (aT + ((size_t)b_ * 4 + (c_ - 8)) * 262144);
  const short* wl = wopw + c_ * 65536;
  int tid = threadIdx.x, wv = tid >> 6, l = tid & 63, lr = l & 15, lg = l >> 4;
  int w0 = wt * 64, G0 = wv * 64;
  f32x4 acc[4][4];
#pragma unroll
  for (int i = 0; i < 4; ++i)
#pragma unroll
    for (int j = 0; j < 4; ++j) acc[i][j] = (f32x4){0.f, 0.f, 0.f, 0.f};
  for (int kc = 0; kc < 256; kc += 32) {
    s16x8 A[4], Bf[4];
#pragma unroll
    for (int s = 0; s < 4; ++s)
      A[s] = *(const s16x8*)(src + (w0 + s * 16 + lr) * 256 + kc + lg * 8);
#pragma unroll
    for (int gs = 0; gs < 4; ++gs)
      Bf[gs] = *(const s16x8*)(wl + (G0 + gs * 16 + lr) * 256 + kc + lg * 8);
#pragma unroll
    for (int s = 0; s < 4; ++s)
#pragma unroll
      for (int gs = 0; gs < 4; ++gs) acc[s][gs] = MFMA16(A[s], Bf[gs], acc[s][gs]);
  }
  short* zp = z + (size_t)bc * 262144;
#pragma unroll
  for (int s = 0; s < 4; ++s) {
    int wb = w0 + s * 16 + lg * 4;
#pragma unroll
    for (int gs = 0; gs < 4; ++gs) {
      int g = G0 + gs * 16 + lr;
      f32x4 v = acc[s][gs];
      uint2 pk;
      pk.x = pack2(v[0], v[1]);
      pk.y = pack2(v[2], v[3]);
      *(uint2*)(zp + g * 1024 + wb) = pk;
    }
  }
}

// ---------------------------------------------------------------------------
// K6: out[b][o][g][w] = sum_c wo_dw[o][c] * z[b][c][g][w]  (vectorized, nt out)
// ---------------------------------------------------------------------------
__global__ __launch_bounds__(256) void k_dw(const short* z, const float* dw, float* out0) {
  __shared__ float wdw[96];
  if (threadIdx.x < 96) wdw[threadIdx.x] = dw[threadIdx.x];
  __syncthreads();
  int id = blockIdx.x * 256 + threadIdx.x;  // 131072 threads, 4 w each
  int w4 = id & 255, g = (id >> 8) & 255, b_ = id >> 16;
  const short* zb = z + ((size_t)b_ * 12) * 262144 + g * 1024 + w4 * 4;
  float zv[12][4];
#pragma unroll
  for (int c = 0; c < 12; ++c) {
    uint2 u = *(const uint2*)(zb + (size_t)c * 262144);
    zv[c][0] = bf2f(u.x & 0xffffu);
    zv[c][1] = bf2f(u.x >> 16);
    zv[c][2] = bf2f(u.y & 0xffffu);
    zv[c][3] = bf2f(u.y >> 16);
  }
  float* ob = out0 + ((size_t)b_ * 8) * 262144 + g * 1024 + w4 * 4;
#pragma unroll
  for (int o = 0; o < 8; ++o) {
    f32x4 s = {0.f, 0.f, 0.f, 0.f};
#pragma unroll
    for (int c = 0; c < 12; ++c) {
      float wc = wdw[o * 12 + c];
      s[0] += wc * zv[c][0];
      s[1] += wc * zv[c][1];
      s[2] += wc * zv[c][2];
      s[3] += wc * zv[c][3];
    }
    __builtin_nontemporal_store(s, (f32x4*)(ob + (size_t)o * 262144));
  }
}

// ---------------------------------------------------------------------------
extern "C" void kernel_launch(void* const* d_in, const int* in_sizes, int n_in,
                              void* d_out, int out_size, void* d_ws, size_t ws_size,
                              hipStream_t stream) {
  const float* x = (const float*)d_in[0];
  const float* prevqk = (const float*)d_in[1];
  const float* wq_conv = (const float*)d_in[2];
  const float* bq = (const float*)d_in[3];
  const float* wq_lin = (const float*)d_in[4];
  const float* wk_conv = (const float*)d_in[5];
  const float* bk = (const float*)d_in[6];
  const float* wk_lin = (const float*)d_in[7];
  const float* wv_conv = (const float*)d_in[8];
  const float* bv = (const float*)d_in[9];
  const float* wv_lin = (const float*)d_in[10];
  const float* wo_pw = (const float*)d_in[11];
  const float* wo_dw = (const float*)d_in[12];

  float* out0 = (float*)d_out;
  float* qkout = out0 + 4194304;  // out[2,8,256,1024] then qk[2,4,8,1024,1024]

  char* ws = (char*)d_ws;
  short* wlin_b = (short*)ws;               // 786432 bf16
  short* wopw_b = wlin_b + 786432;          // 786432 bf16
  float* ct = (float*)(ws + 3145728);       // 16384 f32
  float* st = ct + 16384;                   // 16384 f32
  short* y_b = (short*)(ws + 3276800);      // 6291456 bf16   y[p][b][m][f][w]
  short* yT_b = y_b + 6291456;              // 6291456 bf16   yT[p][b][m][w][f]
  short* q_b = yT_b + 6291456;              // 2097152 bf16   q[b][m][h][w][d] (scaled 1/16)
  short* k_b = q_b + 2097152;               // 2097152 bf16
  short* v_b = k_b + 2097152;               // 2097152 bf16   v[b][m][g][w]
  short* xT_b = v_b + 2097152;              // 4194304 bf16   xT[b][c][w][f]
  short* aT_b = xT_b + 4194304;             // 2097152 bf16   aT[b][m][w][f]
  short* z_b = (short*)(ws + 53608448);     // 6291456 bf16   z[b][c12][g][w]

  k_pre<<<4608, 256, 0, stream>>>(x, wq_lin, wk_lin, wv_lin, wo_pw,
                                  wq_conv, bq, wk_conv, bk, wv_conv, bv,
                                  wlin_b, wopw_b, ct, st, y_b, xT_b);
  k_ty<<<1536, 256, 0, stream>>>(y_b, yT_b);
  k_qkv<<<384, 256, 0, stream>>>(wlin_b, yT_b, ct, st, q_b, k_b, v_b);
  k_attn<<<1024, 256, 0, stream>>>(q_b, k_b, v_b, prevqk, qkout, aT_b);
  k_zproj<<<384, 256, 0, stream>>>(wopw_b, xT_b, aT_b, z_b);
  k_dw<<<512, 256, 0, stream>>>(z_b, wo_dw, out0);
}

// Round 12
// 253.443 us; speedup vs baseline: 1.0060x; 1.0060x over previous
//
#include <hip/hip_runtime.h>
#include <hip/hip_bf16.h>
#include <stdint.h>

// ---------------------------------------------------------------------------
// SpecWaveTransformer on MI355X.
// B=2 C=8 MAPS=4 HEADS=8 F=256 W=1024 HD=32.  Outputs: out[2,8,256,1024] f32,
// qk[2,4,8,1024,1024] f32 (concatenated in d_out).
// ---------------------------------------------------------------------------

typedef __attribute__((ext_vector_type(8))) short s16x8;
typedef __attribute__((ext_vector_type(4))) float f32x4;

#define MFMA16(a, b, c) __builtin_amdgcn_mfma_f32_16x16x32_bf16((a), (b), (c), 0, 0, 0)

__device__ __forceinline__ short f2bf(float f) {
  unsigned u = __builtin_bit_cast(unsigned, f);
  u = (u + 0x7FFFu + ((u >> 16) & 1u)) >> 16;
  return (short)u;
}
__device__ __forceinline__ unsigned pack2(float a, float b) {
  return (unsigned)(unsigned short)f2bf(a) | ((unsigned)(unsigned short)f2bf(b) << 16);
}
__device__ __forceinline__ float bf2f(unsigned u) {
  return __builtin_bit_cast(float, u << 16);
}

// ---------------------------------------------------------------------------
// K0: prep — bf16 casts of linear weights + RoPE cos/sin table [1024][16]
// ---------------------------------------------------------------------------
__global__ __launch_bounds__(256) void k_prep(const float* wq, const float* wk,
                                              const float* wv, const float* wo,
                                              short* wlin, short* wob, float* ct, float* st) {
  int i = blockIdx.x * 256 + threadIdx.x;
  if (i < 262144) wlin[i] = f2bf(wq[i]);
  else if (i < 524288) wlin[i] = f2bf(wk[i - 262144]);
  else if (i < 786432) wlin[i] = f2bf(wv[i - 524288]);
  if (i < 786432) wob[i] = f2bf(wo[i]);
  if (i < 16384) {
    int w = i >> 4, j = i & 15;
    float inv = exp2f(-(float)j * (13.287712379549449f / 16.0f));
    float ang = (float)w * inv;
    ct[i] = cosf(ang);
    st[i] = sinf(ang);
  }
}

// ---------------------------------------------------------------------------
// K1: conv3x3 SAME over (F,W); block = (m, b, f-strip of 4), computes ALL 3 p
// ---------------------------------------------------------------------------
__device__ __forceinline__ void loadrow(float* r, const float* xc, int f, int w0) {
  if (f < 0 || f > 255) {
#pragma unroll
    for (int jj = 0; jj < 6; ++jj) r[jj] = 0.f;
    return;
  }
  const float* row = xc + f * 1024;
#pragma unroll
  for (int jj = 0; jj < 6; ++jj) {
    int wc = w0 - 1 + jj;
    r[jj] = (wc >= 0 && wc < 1024) ? row[wc] : 0.f;
  }
}

__global__ __launch_bounds__(256) void k_conv(const float* x, const float* wqc, const float* bq,
                                              const float* wkc, const float* bk,
                                              const float* wvc, const float* bv, short* y) {
  int blk = blockIdx.x;  // 512 = 4 m * 2 b * 64 fstrips
  int m_ = blk >> 7;
  int b_ = (blk >> 6) & 1;
  int fs = blk & 63;
  int f0 = fs * 4;
  int w0 = threadIdx.x * 4;
  const float* xb = x + (size_t)b_ * 2097152;
  const float* wp_[3] = {wqc + m_ * 72, wkc + m_ * 72, wvc + m_ * 72};
  float bias_[3] = {bq[m_], bk[m_], bv[m_]};

  float acc[3][4][4];
#pragma unroll
  for (int p = 0; p < 3; ++p)
#pragma unroll
    for (int fi = 0; fi < 4; ++fi)
#pragma unroll
      for (int j = 0; j < 4; ++j) acc[p][fi][j] = bias_[p];

  for (int c = 0; c < 8; ++c) {
    const float* xc = xb + c * 262144;
    float w9[3][9];
#pragma unroll
    for (int p = 0; p < 3; ++p)
#pragma unroll
      for (int t = 0; t < 9; ++t) w9[p][t] = wp_[p][c * 9 + t];
    float rows[6][6];
#pragma unroll
    for (int ri = 0; ri < 6; ++ri) loadrow(rows[ri], xc, f0 - 1 + ri, w0);
#pragma unroll
    for (int fi = 0; fi < 4; ++fi) {
#pragma unroll
      for (int p = 0; p < 3; ++p) {
#pragma unroll
        for (int j = 0; j < 4; ++j) {
          float s = acc[p][fi][j];
          s += rows[fi][j] * w9[p][0] + rows[fi][j + 1] * w9[p][1] + rows[fi][j + 2] * w9[p][2];
          s += rows[fi + 1][j] * w9[p][3] + rows[fi + 1][j + 1] * w9[p][4] + rows[fi + 1][j + 2] * w9[p][5];
          s += rows[fi + 2][j] * w9[p][6] + rows[fi + 2][j + 1] * w9[p][7] + rows[fi + 2][j + 2] * w9[p][8];
          acc[p][fi][j] = s;
        }
      }
    }
  }
#pragma unroll
  for (int p = 0; p < 3; ++p) {
    int mat = p * 8 + b_ * 4 + m_;
    short* yp = y + (size_t)mat * 262144;
#pragma unroll
    for (int fi = 0; fi < 4; ++fi) {
      uint2 pk;
      pk.x = pack2(acc[p][fi][0], acc[p][fi][1]);
      pk.y = pack2(acc[p][fi][2], acc[p][fi][3]);
      *(uint2*)(yp + (f0 + fi) * 1024 + w0) = pk;
    }
  }
}

// ---------------------------------------------------------------------------
// K2a/K2b: transposes.  y[f][w] -> yT[w][f] (bf16);  x f32 [f][w] -> xT bf16 [w][f]
// ---------------------------------------------------------------------------
__global__ __launch_bounds__(256) void k_ty(const short* y, short* yT) {
  __shared__ short tile[64][66];
  int blk = blockIdx.x;  // 24 * 64
  int mat = blk >> 6;
  int t = blk & 63;
  int f0 = (t >> 4) * 64, w0 = (t & 15) * 64;
  int j = threadIdx.x & 63, i0 = threadIdx.x >> 6;
  const short* sp = y + (size_t)mat * 262144 + f0 * 1024 + w0;
#pragma unroll
  for (int k = 0; k < 16; ++k) {
    int i = i0 + k * 4;
    tile[j][i] = sp[i * 1024 + j];
  }
  __syncthreads();
  short* dp = yT + (size_t)mat * 262144 + w0 * 256 + f0;
#pragma unroll
  for (int k = 0; k < 16; ++k) {
    int i = i0 + k * 4;
    dp[i * 256 + j] = tile[i][j];
  }
}

__global__ __launch_bounds__(256) void k_tx(const float* x, short* xT) {
  __shared__ short tile[64][66];
  int blk = blockIdx.x;  // 16 * 64
  int mat = blk >> 6;
  int t = blk & 63;
  int f0 = (t >> 4) * 64, w0 = (t & 15) * 64;
  int j = threadIdx.x & 63, i0 = threadIdx.x >> 6;
  const float* sp = x + (size_t)mat * 262144 + f0 * 1024 + w0;
#pragma unroll
  for (int k = 0; k < 16; ++k) {
    int i = i0 + k * 4;
    tile[j][i] = f2bf(sp[i * 1024 + j]);
  }
  __syncthreads();
  short* dp = xT + (size_t)mat * 262144 + w0 * 256 + f0;
#pragma unroll
  for (int k = 0; k < 16; ++k) {
    int i = i0 + k * 4;
    dp[i * 256 + j] = tile[i][j];
  }
}

// ---------------------------------------------------------------------------
// K3: per-map linear (MFMA GEMM) + RoPE (+1/16 scale on Q).
// ---------------------------------------------------------------------------
__global__ __launch_bounds__(256) void k_qkv(const short* wlin, const short* yT,
                                             const float* ct, const float* st,
                                             short* qws, short* kws, short* vws) {
  int blk = blockIdx.x;  // 24 pbm * 16 wtiles
  int pbm = blk >> 4, wt = blk & 15;
  int p = pbm >> 3, bm = pbm & 7;
  int m_ = bm & 3;
  int tid = threadIdx.x, wv = tid >> 6, l = tid & 63, lr = l & 15, lg = l >> 4;
  const short* wl = wlin + (p * 4 + m_) * 65536;
  const short* yp = yT + (size_t)pbm * 262144;
  int w0 = wt * 64;
  int G0 = wv * 64;
  f32x4 acc[4][4];
#pragma unroll
  for (int i = 0; i < 4; ++i)
#pragma unroll
    for (int j = 0; j < 4; ++j) acc[i][j] = (f32x4){0.f, 0.f, 0.f, 0.f};

  if (p < 2) {
    for (int kc = 0; kc < 256; kc += 32) {
      s16x8 A[4], Bf[4];
#pragma unroll
      for (int gs = 0; gs < 4; ++gs)
        A[gs] = *(const s16x8*)(wl + (G0 + gs * 16 + lr) * 256 + kc + lg * 8);
#pragma unroll
      for (int s = 0; s < 4; ++s)
        Bf[s] = *(const s16x8*)(yp + (w0 + s * 16 + lr) * 256 + kc + lg * 8);
#pragma unroll
      for (int gs = 0; gs < 4; ++gs)
#pragma unroll
        for (int s = 0; s < 4; ++s) acc[gs][s] = MFMA16(A[gs], Bf[s], acc[gs][s]);
    }
    short* dst = (p == 0) ? qws : kws;
    float scale = (p == 0) ? 0.0625f : 1.0f;  // fold 1/sqrt(256) into Q
#pragma unroll
    for (int gs = 0; gs < 4; ++gs) {
      int g0v = G0 + gs * 16 + lg * 4;
      int h = g0v >> 5, d0 = g0v & 31;
      int i0 = d0 >> 1;
#pragma unroll
      for (int s = 0; s < 4; ++s) {
        int w = w0 + s * 16 + lr;
        float c0 = ct[w * 16 + i0], sn0 = st[w * 16 + i0];
        float c1 = ct[w * 16 + i0 + 1], sn1 = st[w * 16 + i0 + 1];
        f32x4 v = acc[gs][s];
        float e0 = (v[0] * c0 - v[1] * sn0) * scale;
        float e1 = (v[1] * c0 + v[0] * sn0) * scale;
        float e2 = (v[2] * c1 - v[3] * sn1) * scale;
        float e3 = (v[3] * c1 + v[2] * sn1) * scale;
        uint2 pk;
        pk.x = pack2(e0, e1);
        pk.y = pack2(e2, e3);
        *(uint2*)(dst + (((size_t)bm * 8 + h) * 1024 + w) * 32 + d0) = pk;
      }
    }
  } else {
    for (int kc = 0; kc < 256; kc += 32) {
      s16x8 A[4], Bf[4];
#pragma unroll
      for (int s = 0; s < 4; ++s)
        A[s] = *(const s16x8*)(yp + (w0 + s * 16 + lr) * 256 + kc + lg * 8);
#pragma unroll
      for (int gs = 0; gs < 4; ++gs)
        Bf[gs] = *(const s16x8*)(wl + (G0 + gs * 16 + lr) * 256 + kc + lg * 8);
#pragma unroll
      for (int s = 0; s < 4; ++s)
#pragma unroll
        for (int gs = 0; gs < 4; ++gs) acc[s][gs] = MFMA16(A[s], Bf[gs], acc[s][gs]);
    }
#pragma unroll
    for (int s = 0; s < 4; ++s) {
      int wb = w0 + s * 16 + lg * 4;
#pragma unroll
      for (int gs = 0; gs < 4; ++gs) {
        int g = G0 + gs * 16 + lr;
        f32x4 v = acc[s][gs];
        uint2 pk;
        pk.x = pack2(v[0], v[1]);
        pk.y = pack2(v[2], v[3]);
        *(uint2*)(vws + ((size_t)bm * 256 + g) * 1024 + wb) = pk;
      }
    }
  }
}

// ---------------------------------------------------------------------------
// K4: fused attention — R11 structure, PLAIN stores (single-variable A/B vs
// R11: every nt variant R5-R11 pinned at 2.5-2.7 TB/s; best pre-nt variants
// (R3/R4) were faster; fill (6.9 TB/s) and copy µbench (6.3) use plain
// stores.  Hypothesis: gfx950 nontemporal path hurts write combining and
// drags the interleaved read stream).
// Phase 1: QK^T -> S strip bf16 [16 q][2048B] LDS (XOR swz), per wave.
// Phase 2: rows in 4-row groups, double-buffered bursts.
// Phase 3: PV from P strip + V (L2), normalize, write aT.
// ---------------------------------------------------------------------------
__global__ __launch_bounds__(256, 1) void k_attn(const short* qws, const short* kws,
                                                 const short* vws, const float* prev,
                                                 float* qko, short* aT) {
  __shared__ char smem[131072];  // 4 waves x 32KB S/P strip
  int blk = blockIdx.x;  // 1024 = 64 bmh * 16 qg
  int bmh = blk >> 4;
  int qg = blk & 15;
  int h = bmh & 7, bm = bmh >> 3;
  int tid = threadIdx.x;
  int wv = tid >> 6, l = tid & 63, lr = l & 15, lg = l >> 4;
  int q0 = qg * 64 + wv * 16;
  const short* qp = qws + (size_t)bmh * 32768;
  const short* kp = kws + (size_t)bmh * 32768;
  const short* vp = vws + ((size_t)bm * 256 + h * 32) * 1024;
  const float* pvb = prev + (size_t)bmh * 1048576 + (size_t)q0 * 1024;
  float* qob = qko + (size_t)bmh * 1048576 + (size_t)q0 * 1024;
  char* Sb = smem + wv * 32768;  // byte(q,kb) = q*2048 + (kb ^ ((q&7)<<4))

  s16x8 qf = *(const s16x8*)(qp + (q0 + lr) * 32 + lg * 8);
  const f32x4 z4 = {0.f, 0.f, 0.f, 0.f};

  // ---- Phase 1: QK^T -> S strip (bf16) ----
#pragma unroll
  for (int w = 0; w < 16; ++w) {
    int k0 = w * 64;
    s16x8 kf[4];
#pragma unroll
    for (int s = 0; s < 4; ++s)
      kf[s] = *(const s16x8*)(kp + (k0 + s * 16 + lr) * 32 + lg * 8);
#pragma unroll
    for (int s = 0; s < 4; ++s) {
      f32x4 sx = MFMA16(kf[s], qf, z4);  // lane: q=lr, k=k0+s*16+lg*4+reg
      uint2 pk;
      pk.x = pack2(sx[0], sx[1]);
      pk.y = pack2(sx[2], sx[3]);
      int kb = (k0 + s * 16 + lg * 4) * 2;
      *(uint2*)(Sb + lr * 2048 + (kb ^ ((lr & 7) << 4))) = pk;
    }
  }

  // ---- Phase 2: burst-batched row-IO (4-row groups, double-buffered) ----
  float rs[16];
  f32x4 pA[4][4], pB[4][4];
#pragma unroll
  for (int r4 = 0; r4 < 4; ++r4)
#pragma unroll
    for (int qt = 0; qt < 4; ++qt)
      pA[r4][qt] = *(const f32x4*)(pvb + (size_t)r4 * 1024 + qt * 256 + l * 4);
#pragma unroll
  for (int r4 = 0; r4 < 4; ++r4)
#pragma unroll
    for (int qt = 0; qt < 4; ++qt)
      pB[r4][qt] = *(const f32x4*)(pvb + (size_t)(4 + r4) * 1024 + qt * 256 + l * 4);

#pragma unroll
  for (int g = 0; g < 4; ++g) {
    f32x4(&cur)[4][4] = (g & 1) ? pB : pA;
    // (1) LDS reads + add
    f32x4 v[4][4];
#pragma unroll
    for (int r4 = 0; r4 < 4; ++r4) {
      int r = g * 4 + r4;
#pragma unroll
      for (int qt = 0; qt < 4; ++qt) {
        int sb = (qt * 512 + l * 8) ^ ((r & 7) << 4);
        uint2 su = *(const uint2*)(Sb + r * 2048 + sb);
        f32x4 sv = {bf2f(su.x & 0xffffu), bf2f(su.x >> 16),
                    bf2f(su.y & 0xffffu), bf2f(su.y >> 16)};
        v[r4][qt] = sv + cur[r4][qt];
      }
    }
    // (2) 16-store write burst (PLAIN stores — the A/B variable)
#pragma unroll
    for (int r4 = 0; r4 < 4; ++r4)
#pragma unroll
      for (int qt = 0; qt < 4; ++qt)
        *(f32x4*)(qob + (size_t)(g * 4 + r4) * 1024 + qt * 256 + l * 4) = v[r4][qt];
    // (3) 16-load read burst for group g+2
    if (g < 2) {
#pragma unroll
      for (int r4 = 0; r4 < 4; ++r4)
#pragma unroll
        for (int qt = 0; qt < 4; ++qt)
          cur[r4][qt] = *(const f32x4*)(pvb + (size_t)((g + 2) * 4 + r4) * 1024 + qt * 256 + l * 4);
    }
    // (4) exp + pack + P write + rowsum (pure VALU/LDS)
#pragma unroll
    for (int r4 = 0; r4 < 4; ++r4) {
      int r = g * 4 + r4;
      float sum = 0.f;
#pragma unroll
      for (int qt = 0; qt < 4; ++qt) {
        f32x4 w_ = v[r4][qt];
        float e0 = __expf(w_[0]), e1 = __expf(w_[1]);
        float e2 = __expf(w_[2]), e3 = __expf(w_[3]);
        sum += (e0 + e1) + (e2 + e3);
        uint2 pk;
        pk.x = pack2(e0, e1);
        pk.y = pack2(e2, e3);
        int sb = (qt * 512 + l * 8) ^ ((r & 7) << 4);
        *(uint2*)(Sb + r * 2048 + sb) = pk;  // P in-place over S
      }
      rs[r] = sum;
    }
  }
  // reduce rowsums across all 64 lanes
#pragma unroll
  for (int r = 0; r < 16; ++r) {
    float s = rs[r];
    s += __shfl_xor(s, 1);
    s += __shfl_xor(s, 2);
    s += __shfl_xor(s, 4);
    s += __shfl_xor(s, 8);
    s += __shfl_xor(s, 16);
    s += __shfl_xor(s, 32);
    rs[r] = s;
  }

  // ---- Phase 3: PV from P strip (LDS) + V (L2) ----
  f32x4 o0 = {0.f, 0.f, 0.f, 0.f}, o1 = {0.f, 0.f, 0.f, 0.f};
#pragma unroll
  for (int w = 0; w < 16; ++w) {
    int k0 = w * 64;
#pragma unroll
    for (int kc = 0; kc < 2; ++kc) {
      int kb = (k0 + kc * 32 + lg * 8) * 2;
      s16x8 pa = *(const s16x8*)(Sb + lr * 2048 + (kb ^ ((lr & 7) << 4)));
      s16x8 vf0 = *(const s16x8*)(vp + lr * 1024 + k0 + kc * 32 + lg * 8);
      o0 = MFMA16(pa, vf0, o0);
      s16x8 vf1 = *(const s16x8*)(vp + (16 + lr) * 1024 + k0 + kc * 32 + lg * 8);
      o1 = MFMA16(pa, vf1, o1);
    }
  }
  // normalize: output q-row = lg*4+j (static select)
#pragma unroll
  for (int j = 0; j < 4; ++j) {
    float s = (lg == 0) ? rs[j] : (lg == 1) ? rs[4 + j] : (lg == 2) ? rs[8 + j] : rs[12 + j];
    float inv = 1.0f / s;
    o0[j] *= inv;
    o1[j] *= inv;
  }
  short* ap = aT + (size_t)bm * 262144;
#pragma unroll
  for (int r = 0; r < 4; ++r) {
    int row = q0 + lg * 4 + r;
    ap[row * 256 + h * 32 + lr] = f2bf(o0[r]);
    ap[row * 256 + h * 32 + 16 + lr] = f2bf(o1[r]);
  }
}

// ---------------------------------------------------------------------------
// K5: z[b][c][g][w] = sum_f wo_pw[c][g][f] * cat[b][c][f][w]  (bf16 z output)
// ---------------------------------------------------------------------------
__global__ __launch_bounds__(256) void k_zproj(const short* wopw, const short* xT,
                                               const short* aT, short* z) {
  int blk = blockIdx.x;  // 24 bc * 16 wtiles
  int bc = blk >> 4, wt = blk & 15;
  int b_ = bc / 12, c_ = bc % 12;
  const short* src = (c_ < 8) ? (xT + ((size_t)b_ * 8 + c_) * 262144)
                              : (aT + ((size_t)b_ * 4 + (c_ - 8)) * 262144);
  const short* wl = wopw + c_ * 65536;
  int tid = threadIdx.x, wv = tid >> 6, l = tid & 63, lr = l & 15, lg = l >> 4;
  int w0 = wt * 64, G0 = wv * 64;
  f32x4 acc[4][4];
#pragma unroll
  for (int i = 0; i < 4; ++i)
#pragma unroll
    for (int j = 0; j < 4; ++j) acc[i][j] = (f32x4){0.f, 0.f, 0.f, 0.f};
  for (int kc = 0; kc < 256; kc += 32) {
    s16x8 A[4], Bf[4];
#pragma unroll
    for (int s = 0; s < 4; ++s)
      A[s] = *(const s16x8*)(src + (w0 + s * 16 + lr) * 256 + kc + lg * 8);
#pragma unroll
    for (int gs = 0; gs < 4; ++gs)
      Bf[gs] = *(const s16x8*)(wl + (G0 + gs * 16 + lr) * 256 + kc + lg * 8);
#pragma unroll
    for (int s = 0; s < 4; ++s)
#pragma unroll
      for (int gs = 0; gs < 4; ++gs) acc[s][gs] = MFMA16(A[s], Bf[gs], acc[s][gs]);
  }
  short* zp = z + (size_t)bc * 262144;
#pragma unroll
  for (int s = 0; s < 4; ++s) {
    int wb = w0 + s * 16 + lg * 4;
#pragma unroll
    for (int gs = 0; gs < 4; ++gs) {
      int g = G0 + gs * 16 + lr;
      f32x4 v = acc[s][gs];
      uint2 pk;
      pk.x = pack2(v[0], v[1]);
      pk.y = pack2(v[2], v[3]);
      *(uint2*)(zp + g * 1024 + wb) = pk;
    }
  }
}

// ---------------------------------------------------------------------------
// K6: out[b][o][g][w] = sum_c wo_dw[o][c] * z[b][c][g][w]  (plain stores)
// ---------------------------------------------------------------------------
__global__ __launch_bounds__(256) void k_dw(const short* z, const float* dw, float* out0) {
  __shared__ float wdw[96];
  if (threadIdx.x < 96) wdw[threadIdx.x] = dw[threadIdx.x];
  __syncthreads();
  int id = blockIdx.x * 256 + threadIdx.x;  // 131072 threads, 4 w each
  int w4 = id & 255, g = (id >> 8) & 255, b_ = id >> 16;
  const short* zb = z + ((size_t)b_ * 12) * 262144 + g * 1024 + w4 * 4;
  float zv[12][4];
#pragma unroll
  for (int c = 0; c < 12; ++c) {
    uint2 u = *(const uint2*)(zb + (size_t)c * 262144);
    zv[c][0] = bf2f(u.x & 0xffffu);
    zv[c][1] = bf2f(u.x >> 16);
    zv[c][2] = bf2f(u.y & 0xffffu);
    zv[c][3] = bf2f(u.y >> 16);
  }
  float* ob = out0 + ((size_t)b_ * 8) * 262144 + g * 1024 + w4 * 4;
#pragma unroll
  for (int o = 0; o < 8; ++o) {
    f32x4 s = {0.f, 0.f, 0.f, 0.f};
#pragma unroll
    for (int c = 0; c < 12; ++c) {
      float wc = wdw[o * 12 + c];
      s[0] += wc * zv[c][0];
      s[1] += wc * zv[c][1];
      s[2] += wc * zv[c][2];
      s[3] += wc * zv[c][3];
    }
    *(f32x4*)(ob + (size_t)o * 262144) = s;
  }
}

// ---------------------------------------------------------------------------
extern "C" void kernel_launch(void* const* d_in, const int* in_sizes, int n_in,
                              void* d_out, int out_size, void* d_ws, size_t ws_size,
                              hipStream_t stream) {
  const float* x = (const float*)d_in[0];
  const float* prevqk = (const float*)d_in[1];
  const float* wq_conv = (const float*)d_in[2];
  const float* bq = (const float*)d_in[3];
  const float* wq_lin = (const float*)d_in[4];
  const float* wk_conv = (const float*)d_in[5];
  const float* bk = (const float*)d_in[6];
  const float* wk_lin = (const float*)d_in[7];
  const float* wv_conv = (const float*)d_in[8];
  const float* bv = (const float*)d_in[9];
  const float* wv_lin = (const float*)d_in[10];
  const float* wo_pw = (const float*)d_in[11];
  const float* wo_dw = (const float*)d_in[12];

  float* out0 = (float*)d_out;
  float* qkout = out0 + 4194304;  // out[2,8,256,1024] then qk[2,4,8,1024,1024]

  char* ws = (char*)d_ws;
  short* wlin_b = (short*)ws;               // 786432 bf16
  short* wopw_b = wlin_b + 786432;          // 786432 bf16
  float* ct = (float*)(ws + 3145728);       // 16384 f32
  float* st = ct + 16384;                   // 16384 f32
  short* y_b = (short*)(ws + 3276800);      // 6291456 bf16   y[p][b][m][f][w]
  short* yT_b = y_b + 6291456;              // 6291456 bf16   yT[p][b][m][w][f]
  short* q_b = yT_b + 6291456;              // 2097152 bf16   q[b][m][h][w][d] (scaled 1/16)
  short* k_b = q_b + 2097152;               // 2097152 bf16
  short* v_b = k_b + 2097152;               // 2097152 bf16   v[b][m][g][w]
  short* xT_b = v_b + 2097152;              // 4194304 bf16   xT[b][c][w][f]
  short* aT_b = xT_b + 4194304;             // 2097152 bf16   aT[b][m][w][f]
  short* z_b = (short*)(ws + 53608448);     // 6291456 bf16   z[b][c12][g][w]

  k_prep<<<3072, 256, 0, stream>>>(wq_lin, wk_lin, wv_lin, wo_pw, wlin_b, wopw_b, ct, st);
  k_conv<<<512, 256, 0, stream>>>(x, wq_conv, bq, wk_conv, bk, wv_conv, bv, y_b);
  k_ty<<<1536, 256, 0, stream>>>(y_b, yT_b);
  k_tx<<<1024, 256, 0, stream>>>(x, xT_b);
  k_qkv<<<384, 256, 0, stream>>>(wlin_b, yT_b, ct, st, q_b, k_b, v_b);
  k_attn<<<1024, 256, 0, stream>>>(q_b, k_b, v_b, prevqk, qkout, aT_b);
  k_zproj<<<384, 256, 0, stream>>>(wopw_b, xT_b, aT_b, z_b);
  k_dw<<<512, 256, 0, stream>>>(z_b, wo_dw, out0);
}

// Round 13
// 220.647 us; speedup vs baseline: 1.1555x; 1.1486x over previous
//
#include <hip/hip_runtime.h>
#include <hip/hip_bf16.h>
#include <stdint.h>

// ---------------------------------------------------------------------------
// SpecWaveTransformer on MI355X.
// B=2 C=8 MAPS=4 HEADS=8 F=256 W=1024 HD=32.  Outputs: out[2,8,256,1024] f32,
// qk[2,4,8,1024,1024] f32 (concatenated in d_out).
// Attn mixed read+write stream empirically pinned at ~2.6 TB/s (R2-R12
// invariance); this round optimizes the non-attn tail (transpose fusion).
// ---------------------------------------------------------------------------

typedef __attribute__((ext_vector_type(8))) short s16x8;
typedef __attribute__((ext_vector_type(4))) float f32x4;

#define MFMA16(a, b, c) __builtin_amdgcn_mfma_f32_16x16x32_bf16((a), (b), (c), 0, 0, 0)

__device__ __forceinline__ short f2bf(float f) {
  unsigned u = __builtin_bit_cast(unsigned, f);
  u = (u + 0x7FFFu + ((u >> 16) & 1u)) >> 16;
  return (short)u;
}
__device__ __forceinline__ unsigned pack2(float a, float b) {
  return (unsigned)(unsigned short)f2bf(a) | ((unsigned)(unsigned short)f2bf(b) << 16);
}
__device__ __forceinline__ float bf2f(unsigned u) {
  return __builtin_bit_cast(float, u << 16);
}

// ---------------------------------------------------------------------------
// K0: prep — bf16 casts of linear weights + RoPE cos/sin table [1024][16]
// ---------------------------------------------------------------------------
__global__ __launch_bounds__(256) void k_prep(const float* wq, const float* wk,
                                              const float* wv, const float* wo,
                                              short* wlin, short* wob, float* ct, float* st) {
  int i = blockIdx.x * 256 + threadIdx.x;
  if (i < 262144) wlin[i] = f2bf(wq[i]);
  else if (i < 524288) wlin[i] = f2bf(wk[i - 262144]);
  else if (i < 786432) wlin[i] = f2bf(wv[i - 524288]);
  if (i < 786432) wob[i] = f2bf(wo[i]);
  if (i < 16384) {
    int w = i >> 4, j = i & 15;
    float inv = exp2f(-(float)j * (13.287712379549449f / 16.0f));
    float ang = (float)w * inv;
    ct[i] = cosf(ang);
    st[i] = sinf(ang);
  }
}

// ---------------------------------------------------------------------------
// K1: conv3x3 SAME over (F,W); block = (m, b, f-strip of 4), computes ALL 3 p
// ---------------------------------------------------------------------------
__device__ __forceinline__ void loadrow(float* r, const float* xc, int f, int w0) {
  if (f < 0 || f > 255) {
#pragma unroll
    for (int jj = 0; jj < 6; ++jj) r[jj] = 0.f;
    return;
  }
  const float* row = xc + f * 1024;
#pragma unroll
  for (int jj = 0; jj < 6; ++jj) {
    int wc = w0 - 1 + jj;
    r[jj] = (wc >= 0 && wc < 1024) ? row[wc] : 0.f;
  }
}

__global__ __launch_bounds__(256) void k_conv(const float* x, const float* wqc, const float* bq,
                                              const float* wkc, const float* bk,
                                              const float* wvc, const float* bv, short* y) {
  int blk = blockIdx.x;  // 512 = 4 m * 2 b * 64 fstrips
  int m_ = blk >> 7;
  int b_ = (blk >> 6) & 1;
  int fs = blk & 63;
  int f0 = fs * 4;
  int w0 = threadIdx.x * 4;
  const float* xb = x + (size_t)b_ * 2097152;
  const float* wp_[3] = {wqc + m_ * 72, wkc + m_ * 72, wvc + m_ * 72};
  float bias_[3] = {bq[m_], bk[m_], bv[m_]};

  float acc[3][4][4];
#pragma unroll
  for (int p = 0; p < 3; ++p)
#pragma unroll
    for (int fi = 0; fi < 4; ++fi)
#pragma unroll
      for (int j = 0; j < 4; ++j) acc[p][fi][j] = bias_[p];

  for (int c = 0; c < 8; ++c) {
    const float* xc = xb + c * 262144;
    float w9[3][9];
#pragma unroll
    for (int p = 0; p < 3; ++p)
#pragma unroll
      for (int t = 0; t < 9; ++t) w9[p][t] = wp_[p][c * 9 + t];
    float rows[6][6];
#pragma unroll
    for (int ri = 0; ri < 6; ++ri) loadrow(rows[ri], xc, f0 - 1 + ri, w0);
#pragma unroll
    for (int fi = 0; fi < 4; ++fi) {
#pragma unroll
      for (int p = 0; p < 3; ++p) {
#pragma unroll
        for (int j = 0; j < 4; ++j) {
          float s = acc[p][fi][j];
          s += rows[fi][j] * w9[p][0] + rows[fi][j + 1] * w9[p][1] + rows[fi][j + 2] * w9[p][2];
          s += rows[fi + 1][j] * w9[p][3] + rows[fi + 1][j + 1] * w9[p][4] + rows[fi + 1][j + 2] * w9[p][5];
          s += rows[fi + 2][j] * w9[p][6] + rows[fi + 2][j + 1] * w9[p][7] + rows[fi + 2][j + 2] * w9[p][8];
          acc[p][fi][j] = s;
        }
      }
    }
  }
#pragma unroll
  for (int p = 0; p < 3; ++p) {
    int mat = p * 8 + b_ * 4 + m_;
    short* yp = y + (size_t)mat * 262144;
#pragma unroll
    for (int fi = 0; fi < 4; ++fi) {
      uint2 pk;
      pk.x = pack2(acc[p][fi][0], acc[p][fi][1]);
      pk.y = pack2(acc[p][fi][2], acc[p][fi][3]);
      *(uint2*)(yp + (f0 + fi) * 1024 + w0) = pk;
    }
  }
}

// ---------------------------------------------------------------------------
// K3: per-map linear (MFMA GEMM) + RoPE, with FUSED y-transpose (kills k_ty).
// Stage y[f][w-window] -> ytile[w][f] (padded stride 264 shorts = 528B,
// 16B-aligned rows; 2-way-or-free LDS banking both sides).
// ---------------------------------------------------------------------------
__global__ __launch_bounds__(256) void k_qkv(const short* wlin, const short* y,
                                             const float* ct, const float* st,
                                             short* qws, short* kws, short* vws) {
  __shared__ short ytile[64][264];
  int blk = blockIdx.x;  // 24 pbm * 16 wtiles
  int pbm = blk >> 4, wt = blk & 15;
  int p = pbm >> 3, bm = pbm & 7;
  int m_ = bm & 3;
  int tid = threadIdx.x, wv = tid >> 6, l = tid & 63, lr = l & 15, lg = l >> 4;
  const short* wl = wlin + (p * 4 + m_) * 65536;
  const short* yp = y + (size_t)pbm * 262144;
  int w0 = wt * 64;
  int G0 = wv * 64;

  // ---- stage + transpose: wave wv covers f rows [wv*64, wv*64+64) ----
  {
    int h2 = l >> 5, lih = l & 31;
#pragma unroll
    for (int i = 0; i < 32; ++i) {
      int f = wv * 64 + i * 2 + h2;
      unsigned u = *(const unsigned*)(yp + f * 1024 + w0 + lih * 2);
      ytile[lih * 2][f] = (short)(u & 0xffffu);
      ytile[lih * 2 + 1][f] = (short)(u >> 16);
    }
  }
  __syncthreads();

  f32x4 acc[4][4];
#pragma unroll
  for (int i = 0; i < 4; ++i)
#pragma unroll
    for (int j = 0; j < 4; ++j) acc[i][j] = (f32x4){0.f, 0.f, 0.f, 0.f};

  if (p < 2) {
    for (int kc = 0; kc < 256; kc += 32) {
      s16x8 A[4], Bf[4];
#pragma unroll
      for (int gs = 0; gs < 4; ++gs)
        A[gs] = *(const s16x8*)(wl + (G0 + gs * 16 + lr) * 256 + kc + lg * 8);
#pragma unroll
      for (int s = 0; s < 4; ++s)
        Bf[s] = *(const s16x8*)(&ytile[s * 16 + lr][kc + lg * 8]);
#pragma unroll
      for (int gs = 0; gs < 4; ++gs)
#pragma unroll
        for (int s = 0; s < 4; ++s) acc[gs][s] = MFMA16(A[gs], Bf[s], acc[gs][s]);
    }
    short* dst = (p == 0) ? qws : kws;
    float scale = (p == 0) ? 0.0625f : 1.0f;  // fold 1/sqrt(256) into Q
#pragma unroll
    for (int gs = 0; gs < 4; ++gs) {
      int g0v = G0 + gs * 16 + lg * 4;
      int h = g0v >> 5, d0 = g0v & 31;
      int i0 = d0 >> 1;
#pragma unroll
      for (int s = 0; s < 4; ++s) {
        int w = w0 + s * 16 + lr;
        float c0 = ct[w * 16 + i0], sn0 = st[w * 16 + i0];
        float c1 = ct[w * 16 + i0 + 1], sn1 = st[w * 16 + i0 + 1];
        f32x4 v = acc[gs][s];
        float e0 = (v[0] * c0 - v[1] * sn0) * scale;
        float e1 = (v[1] * c0 + v[0] * sn0) * scale;
        float e2 = (v[2] * c1 - v[3] * sn1) * scale;
        float e3 = (v[3] * c1 + v[2] * sn1) * scale;
        uint2 pk;
        pk.x = pack2(e0, e1);
        pk.y = pack2(e2, e3);
        *(uint2*)(dst + (((size_t)bm * 8 + h) * 1024 + w) * 32 + d0) = pk;
      }
    }
  } else {
    for (int kc = 0; kc < 256; kc += 32) {
      s16x8 A[4], Bf[4];
#pragma unroll
      for (int s = 0; s < 4; ++s)
        A[s] = *(const s16x8*)(&ytile[s * 16 + lr][kc + lg * 8]);
#pragma unroll
      for (int gs = 0; gs < 4; ++gs)
        Bf[gs] = *(const s16x8*)(wl + (G0 + gs * 16 + lr) * 256 + kc + lg * 8);
#pragma unroll
      for (int s = 0; s < 4; ++s)
#pragma unroll
        for (int gs = 0; gs < 4; ++gs) acc[s][gs] = MFMA16(A[s], Bf[gs], acc[s][gs]);
    }
#pragma unroll
    for (int s = 0; s < 4; ++s) {
      int wb = w0 + s * 16 + lg * 4;
#pragma unroll
      for (int gs = 0; gs < 4; ++gs) {
        int g = G0 + gs * 16 + lr;
        f32x4 v = acc[s][gs];
        uint2 pk;
        pk.x = pack2(v[0], v[1]);
        pk.y = pack2(v[2], v[3]);
        *(uint2*)(vws + ((size_t)bm * 256 + g) * 1024 + wb) = pk;
      }
    }
  }
}

// ---------------------------------------------------------------------------
// K4: fused attention (verbatim R9 — best measured attn, 165us).
// K+V staged to LDS once per block; steady-state vmem = prev read stream
// (register-prefetched 2 windows deep) + qk store stream.  4 waves/block,
// 1 block/CU (152KB static LDS), zero in-loop barriers, wave-private panels.
// ---------------------------------------------------------------------------
__global__ __launch_bounds__(256, 1) void k_attn(const short* qws, const short* kws,
                                                 const short* vws, const float* prev,
                                                 float* qko, short* aT) {
  __shared__ char smem[155648];
  // LDS: K [0,64K): row k(1024) x 64B, xor ((k&3)<<4)
  //      V [64K,128K): row g(32) x 2048B, xor ((g&7)<<4)
  //      S [128K + wv*4K): 16 q x 256B, xor ((q&7)<<4)
  //      P [144K + wv*2K): 16 q x 128B, xor ((q&7)<<4)
  int blk = blockIdx.x;  // 1024 = 64 bmh * 16 qg
  int bmh = blk >> 4;
  int qg = blk & 15;
  int h = bmh & 7, bm = bmh >> 3;
  int tid = threadIdx.x;
  int wv = tid >> 6, l = tid & 63, lr = l & 15, lg = l >> 4;
  const short* kp = kws + (size_t)bmh * 32768;
  const short* vp = vws + ((size_t)bm * 256 + h * 32) * 1024;

  // ---- stage K (64KB): 16 iters, 64 rows x 64B each (256 thr x 16B) ----
  {
    int row4 = tid >> 2, c = tid & 3;
#pragma unroll
    for (int i = 0; i < 16; ++i) {
      int row = i * 64 + row4;
      s16x8 kv = *(const s16x8*)(kp + row * 32 + c * 8);
      *(s16x8*)(smem + row * 64 + ((c * 16) ^ ((row & 3) << 4))) = kv;
    }
    // ---- stage V (64KB): 16 iters, 2 rows x 2048B each ----
    int g2 = tid >> 7, cb = (tid & 127) * 16;
#pragma unroll
    for (int i = 0; i < 16; ++i) {
      int g = i * 2 + g2;
      s16x8 vv = *(const s16x8*)(vp + g * 1024 + (cb >> 1));
      *(s16x8*)(smem + 65536 + g * 2048 + (cb ^ ((g & 7) << 4))) = vv;
    }
  }
  __syncthreads();

  int q0 = qg * 64 + wv * 16;
  const short* qp = qws + (size_t)bmh * 32768;
  s16x8 qf = *(const s16x8*)(qp + (q0 + lr) * 32 + lg * 8);
  char* Sb = smem + 131072 + wv * 4096;
  char* Pb = smem + 147456 + wv * 2048;
  const float* pvb = prev + (size_t)bmh * 1048576 + (size_t)q0 * 1024;
  float* qob = qko + (size_t)bmh * 1048576 + (size_t)q0 * 1024;
  int pcol = (l & 15) * 4;   // float col within window
  int pcolb = pcol * 4;      // byte col within S row
  f32x4 o0 = {0.f, 0.f, 0.f, 0.f}, o1 = {0.f, 0.f, 0.f, 0.f};
  f32x4 rs = {0.f, 0.f, 0.f, 0.f};  // rs[j]: rowsum partial for q-row j*4+lg
  const f32x4 z4 = {0.f, 0.f, 0.f, 0.f};

  // window body: consume pr (window w), refill pr with window w+2
  auto attn_win = [&](int w, f32x4(&pr)[4]) {
    int k0 = w * 64;
    // QK^T from LDS K
#pragma unroll
    for (int s = 0; s < 4; ++s) {
      int krow = k0 + s * 16 + lr;
      s16x8 kf = *(const s16x8*)(smem + krow * 64 + ((lg * 16) ^ ((krow & 3) << 4)));
      f32x4 sx = MFMA16(kf, qf, z4);  // lane: q=lr(col), k=k0+s*16+lg*4+reg
      *(f32x4*)(Sb + lr * 256 + ((s * 64 + lg * 16) ^ ((lr & 7) << 4))) = sx;
    }
    // row-IO: instr j covers q-rows j*4..j*4+3 (lane: row j*4+lg, 16B of cols)
#pragma unroll
    for (int j = 0; j < 4; ++j) {
      int qr = j * 4 + lg;
      f32x4 sv = *(const f32x4*)(Sb + qr * 256 + (pcolb ^ ((qr & 7) << 4)));
      f32x4 v = sv + pr[j];
      *(f32x4*)(qob + (size_t)qr * 1024 + k0 + pcol) = v;
      float e0 = __expf(v[0]), e1 = __expf(v[1]);
      float e2 = __expf(v[2]), e3 = __expf(v[3]);
      rs[j] += (e0 + e1) + (e2 + e3);
      uint2 pk;
      pk.x = pack2(e0, e1);
      pk.y = pack2(e2, e3);
      *(uint2*)(Pb + qr * 128 + (((l & 15) * 8) ^ ((qr & 7) << 4))) = pk;
    }
    // refill prefetch (2 windows ahead)
    if (w + 2 < 16) {
#pragma unroll
      for (int j = 0; j < 4; ++j)
        pr[j] = *(const f32x4*)(pvb + (size_t)(j * 4 + lg) * 1024 + (w + 2) * 64 + pcol);
    }
    // PV from LDS V
#pragma unroll
    for (int kc = 0; kc < 2; ++kc) {
      s16x8 pa = *(const s16x8*)(Pb + lr * 128 + ((kc * 64 + lg * 16) ^ ((lr & 7) << 4)));
      int kcb = (k0 + kc * 32 + lg * 8) * 2;
      s16x8 vf0 = *(const s16x8*)(smem + 65536 + lr * 2048 + (kcb ^ ((lr & 7) << 4)));
      o0 = MFMA16(pa, vf0, o0);
      s16x8 vf1 = *(const s16x8*)(smem + 65536 + (16 + lr) * 2048 + (kcb ^ ((lr & 7) << 4)));
      o1 = MFMA16(pa, vf1, o1);
    }
  };

  f32x4 pA[4], pB[4];
#pragma unroll
  for (int j = 0; j < 4; ++j)
    pA[j] = *(const f32x4*)(pvb + (size_t)(j * 4 + lg) * 1024 + 0 + pcol);
#pragma unroll
  for (int j = 0; j < 4; ++j)
    pB[j] = *(const f32x4*)(pvb + (size_t)(j * 4 + lg) * 1024 + 64 + pcol);

  for (int w = 0; w < 16; w += 2) {
    attn_win(w, pA);
    attn_win(w + 1, pB);
  }

  // rowsum reduce across the 16 lanes sharing lg
#pragma unroll
  for (int j = 0; j < 4; ++j) {
    float s = rs[j];
    s += __shfl_xor(s, 1);
    s += __shfl_xor(s, 2);
    s += __shfl_xor(s, 4);
    s += __shfl_xor(s, 8);
    rs[j] = s;
  }
  // route rowsums to PV-frag layout via wave-private S scratch
  if (lr == 0) {
#pragma unroll
    for (int j = 0; j < 4; ++j) *(float*)(Sb + (j * 4 + lg) * 4) = rs[j];
  }
  f32x4 sums = *(const f32x4*)(Sb + lg * 16);
  f32x4 inv = {1.f / sums[0], 1.f / sums[1], 1.f / sums[2], 1.f / sums[3]};
  o0 *= inv;
  o1 *= inv;
  short* ap = aT + (size_t)bm * 262144;
#pragma unroll
  for (int r = 0; r < 4; ++r) {
    int row = q0 + lg * 4 + r;
    ap[row * 256 + h * 32 + lr] = f2bf(o0[r]);
    ap[row * 256 + h * 32 + 16 + lr] = f2bf(o1[r]);
  }
}

// ---------------------------------------------------------------------------
// K5: z projection with FUSED x-transpose (kills k_tx).
// c<8: stage x f32 [f][w-window] -> bf16 xtile[w][f]; c>=8: aT already [w][f].
// ---------------------------------------------------------------------------
__global__ __launch_bounds__(256) void k_zproj(const short* wopw, const float* x,
                                               const short* aT, short* z) {
  __shared__ short xtile[64][264];
  int blk = blockIdx.x;  // 24 bc * 16 wtiles
  int bc = blk >> 4, wt = blk & 15;
  int b_ = bc / 12, c_ = bc % 12;
  const short* wl = wopw + c_ * 65536;
  int tid = threadIdx.x, wv = tid >> 6, l = tid & 63, lr = l & 15, lg = l >> 4;
  int w0 = wt * 64, G0 = wv * 64;
  bool use_lds = (c_ < 8);
  const short* asrc = aT + ((size_t)b_ * 4 + (c_ - 8)) * 262144;

  if (use_lds) {
    const float* xp = x + ((size_t)b_ * 8 + c_) * 262144;
    int h2 = l >> 5, lih = l & 31;
#pragma unroll
    for (int i = 0; i < 32; ++i) {
      int f = wv * 64 + i * 2 + h2;
      uint2 u = *(const uint2*)(xp + f * 1024 + w0 + lih * 2);
      xtile[lih * 2][f] = f2bf(__builtin_bit_cast(float, u.x));
      xtile[lih * 2 + 1][f] = f2bf(__builtin_bit_cast(float, u.y));
    }
  }
  __syncthreads();

  f32x4 acc[4][4];
#pragma unroll
  for (int i = 0; i < 4; ++i)
#pragma unroll
    for (int j = 0; j < 4; ++j) acc[i][j] = (f32x4){0.f, 0.f, 0.f, 0.f};
  for (int kc = 0; kc < 256; kc += 32) {
    s16x8 A[4], Bf[4];
#pragma unroll
    for (int s = 0; s < 4; ++s)
      A[s] = use_lds ? *(const s16x8*)(&xtile[s * 16 + lr][kc + lg * 8])
                     : *(const s16x8*)(asrc + (w0 + s * 16 + lr) * 256 + kc + lg * 8);
#pragma unroll
    for (int gs = 0; gs < 4; ++gs)
      Bf[gs] = *(const s16x8*)(wl + (G0 + gs * 16 + lr) * 256 + kc + lg * 8);
#pragma unroll
    for (int s = 0; s < 4; ++s)
#pragma unroll
      for (int gs = 0; gs < 4; ++gs) acc[s][gs] = MFMA16(A[s], Bf[gs], acc[s][gs]);
  }
  short* zp = z + (size_t)bc * 262144;
#pragma unroll
  for (int s = 0; s < 4; ++s) {
    int wb = w0 + s * 16 + lg * 4;
#pragma unroll
    for (int gs = 0; gs < 4; ++gs) {
      int g = G0 + gs * 16 + lr;
      f32x4 v = acc[s][gs];
      uint2 pk;
      pk.x = pack2(v[0], v[1]);
      pk.y = pack2(v[2], v[3]);
      *(uint2*)(zp + g * 1024 + wb) = pk;
    }
  }
}

// ---------------------------------------------------------------------------
// K6: out[b][o][g][w] = sum_c wo_dw[o][c] * z[b][c][g][w]
// ---------------------------------------------------------------------------
__global__ __launch_bounds__(256) void k_dw(const short* z, const float* dw, float* out0) {
  __shared__ float wdw[96];
  if (threadIdx.x < 96) wdw[threadIdx.x] = dw[threadIdx.x];
  __syncthreads();
  int id = blockIdx.x * 256 + threadIdx.x;  // 131072 threads, 4 w each
  int w4 = id & 255, g = (id >> 8) & 255, b_ = id >> 16;
  const short* zb = z + ((size_t)b_ * 12) * 262144 + g * 1024 + w4 * 4;
  float zv[12][4];
#pragma unroll
  for (int c = 0; c < 12; ++c) {
    uint2 u = *(const uint2*)(zb + (size_t)c * 262144);
    zv[c][0] = bf2f(u.x & 0xffffu);
    zv[c][1] = bf2f(u.x >> 16);
    zv[c][2] = bf2f(u.y & 0xffffu);
    zv[c][3] = bf2f(u.y >> 16);
  }
  float* ob = out0 + ((size_t)b_ * 8) * 262144 + g * 1024 + w4 * 4;
#pragma unroll
  for (int o = 0; o < 8; ++o) {
    f32x4 s = {0.f, 0.f, 0.f, 0.f};
#pragma unroll
    for (int c = 0; c < 12; ++c) {
      float wc = wdw[o * 12 + c];
      s[0] += wc * zv[c][0];
      s[1] += wc * zv[c][1];
      s[2] += wc * zv[c][2];
      s[3] += wc * zv[c][3];
    }
    *(f32x4*)(ob + (size_t)o * 262144) = s;
  }
}

// ---------------------------------------------------------------------------
extern "C" void kernel_launch(void* const* d_in, const int* in_sizes, int n_in,
                              void* d_out, int out_size, void* d_ws, size_t ws_size,
                              hipStream_t stream) {
  const float* x = (const float*)d_in[0];
  const float* prevqk = (const float*)d_in[1];
  const float* wq_conv = (const float*)d_in[2];
  const float* bq = (const float*)d_in[3];
  const float* wq_lin = (const float*)d_in[4];
  const float* wk_conv = (const float*)d_in[5];
  const float* bk = (const float*)d_in[6];
  const float* wk_lin = (const float*)d_in[7];
  const float* wv_conv = (const float*)d_in[8];
  const float* bv = (const float*)d_in[9];
  const float* wv_lin = (const float*)d_in[10];
  const float* wo_pw = (const float*)d_in[11];
  const float* wo_dw = (const float*)d_in[12];

  float* out0 = (float*)d_out;
  float* qkout = out0 + 4194304;  // out[2,8,256,1024] then qk[2,4,8,1024,1024]

  char* ws = (char*)d_ws;
  short* wlin_b = (short*)ws;               // 786432 bf16
  short* wopw_b = wlin_b + 786432;          // 786432 bf16
  float* ct = (float*)(ws + 3145728);       // 16384 f32
  float* st = ct + 16384;                   // 16384 f32
  short* y_b = (short*)(ws + 3276800);      // 6291456 bf16   y[p][b][m][f][w]
  short* q_b = y_b + 6291456;               // 2097152 bf16   q[b][m][h][w][d] (scaled 1/16)
  short* k_b = q_b + 2097152;               // 2097152 bf16
  short* v_b = k_b + 2097152;               // 2097152 bf16   v[b][m][g][w]
  short* aT_b = v_b + 2097152;              // 2097152 bf16   aT[b][m][w][f]
  short* z_b = (short*)(ws + 53608448);     // 6291456 bf16   z[b][c12][g][w]

  k_prep<<<3072, 256, 0, stream>>>(wq_lin, wk_lin, wv_lin, wo_pw, wlin_b, wopw_b, ct, st);
  k_conv<<<512, 256, 0, stream>>>(x, wq_conv, bq, wk_conv, bk, wv_conv, bv, y_b);
  k_qkv<<<384, 256, 0, stream>>>(wlin_b, y_b, ct, st, q_b, k_b, v_b);
  k_attn<<<1024, 256, 0, stream>>>(q_b, k_b, v_b, prevqk, qkout, aT_b);
  k_zproj<<<384, 256, 0, stream>>>(wopw_b, x, aT_b, z_b);
  k_dw<<<512, 256, 0, stream>>>(z_b, wo_dw, out0);
}